// Round 1
// baseline (165.067 us; speedup 1.0000x reference)
//
#include <hip/hip_runtime.h>

#define BATCH 2
#define NM_PER_B 9375      // 3*25*5*25
#define C_STRIDE 3125      // 25*5*25
#define I_STRIDE 125       // 5*25
#define TOP_OFF 100        // row index 4 (== -1) of dim 5: 4*25
#define RES 73             // (25-1)*3 + 1
#define N_TOP 5329         // 73*73
#define M_PC 8192
#define PC_PER_B 24576     // 3*8192

#define NSEG 8
#define SEG_N 667          // ceil(5329/8)
#define SEG_M 1024         // 8192/8

// ws layout (floats): dist1 [0, 10658) padded to 10752; dist2 [10752, 10752+16384)
#define DIST2_OFF 10752
#define DIST_TOTAL_FLOATS (10752 + 16384)

// Align-corners factor-3 bilinear sample of network_mesh[b, c, :, 4, :] at
// refined index n = u*73 + v.  Matches reference's separable order
// (axis=3 lerp first, then axis=2 lerp).
__device__ __forceinline__ float3 top_point(const float* __restrict__ nm, int b, int n) {
    int u = n / RES, v = n - u * RES;
    int iu = u / 3, ru = u - iu * 3;
    int iv = v / 3, rv = v - iv * 3;
    float fu = (float)ru / 3.0f;
    float fv = (float)rv / 3.0f;
    int iu2 = iu < 24 ? iu + 1 : 24;
    int iv2 = iv < 24 ? iv + 1 : 24;
    float gu = 1.0f - fu, gv = 1.0f - fv;
    const float* base = nm + b * NM_PER_B + TOP_OFF;
    float r[3];
    #pragma unroll
    for (int c = 0; c < 3; ++c) {
        const float* a = base + c * C_STRIDE;
        float a00 = a[iu * I_STRIDE + iv];
        float a01 = a[iu * I_STRIDE + iv2];
        float a10 = a[iu2 * I_STRIDE + iv];
        float a11 = a[iu2 * I_STRIDE + iv2];
        float t0 = a00 * gv + a01 * fv;
        float t1 = a10 * gv + a11 * fv;
        r[c] = t0 * gu + t1 * fu;
    }
    return make_float3(r[0], r[1], r[2]);
}

// Block roles:
//   blocks [0, 512):   task A — dist2[m] = min over one n-segment (top staged in LDS)
//   blocks [512, 848): task B — dist1[n] = min over one m-segment (pc staged in LDS)
__global__ __launch_bounds__(256) void pair_kernel(const float* __restrict__ nm,
                                                   const float* __restrict__ pc,
                                                   unsigned int* __restrict__ dist1,
                                                   unsigned int* __restrict__ dist2) {
    __shared__ float sx[SEG_M];
    __shared__ float sy[SEG_M];
    __shared__ float sz[SEG_M];
    const int blk = blockIdx.x;
    const int tid = threadIdx.x;

    if (blk < 512) {
        // ---- task A: per-m min over an n-segment ----
        const int b = blk >> 8;            // 256 blocks per batch
        const int r = blk & 255;
        const int mchunk = r >> 3;         // 0..31
        const int seg = r & 7;             // 0..7
        const int n0 = seg * SEG_N;
        const int n1 = min(n0 + SEG_N, N_TOP);
        const int cnt = n1 - n0;

        for (int idx = tid; idx < cnt; idx += 256) {
            float3 p = top_point(nm, b, n0 + idx);
            sx[idx] = p.x; sy[idx] = p.y; sz[idx] = p.z;
        }
        __syncthreads();

        const int m = (mchunk << 8) + tid;
        const float* pcb = pc + b * PC_PER_B;
        const float px = pcb[m];
        const float py = pcb[M_PC + m];
        const float pz = pcb[2 * M_PC + m];
        float mn = 3.4e38f;
        #pragma unroll 4
        for (int j = 0; j < cnt; ++j) {
            float dx = px - sx[j];
            float dy = py - sy[j];
            float dz = pz - sz[j];
            float d2 = fmaf(dx, dx, fmaf(dy, dy, dz * dz));
            mn = fminf(mn, d2);
        }
        atomicMin(&dist2[b * M_PC + m], __float_as_uint(mn));
    } else {
        // ---- task B: per-n min over an m-segment ----
        const int t = blk - 512;           // 0..335
        const int b = t / 168;             // 21*8 = 168 blocks per batch
        const int r = t - b * 168;
        const int nchunk = r >> 3;         // 0..20
        const int seg = r & 7;             // 0..7
        const int m0 = seg * SEG_M;

        const float* pcb = pc + b * PC_PER_B + m0;
        // 1024 floats per coordinate row, 256 threads -> one float4 each
        reinterpret_cast<float4*>(sx)[tid] = reinterpret_cast<const float4*>(pcb)[tid];
        reinterpret_cast<float4*>(sy)[tid] = reinterpret_cast<const float4*>(pcb + M_PC)[tid];
        reinterpret_cast<float4*>(sz)[tid] = reinterpret_cast<const float4*>(pcb + 2 * M_PC)[tid];
        __syncthreads();

        const int n = (nchunk << 8) + tid;
        float3 p = make_float3(0.f, 0.f, 0.f);
        if (n < N_TOP) p = top_point(nm, b, n);
        float mn = 3.4e38f;
        #pragma unroll 4
        for (int j = 0; j < SEG_M; ++j) {
            float dx = p.x - sx[j];
            float dy = p.y - sy[j];
            float dz = p.z - sz[j];
            float d2 = fmaf(dx, dx, fmaf(dy, dy, dz * dz));
            mn = fminf(mn, d2);
        }
        if (n < N_TOP) atomicMin(&dist1[b * N_TOP + n], __float_as_uint(mn));
    }
}

__global__ __launch_bounds__(1024) void finalize_kernel(const float* __restrict__ nm,
                                                        const float* __restrict__ fm,
                                                        const float* __restrict__ dist1,
                                                        const float* __restrict__ dist2,
                                                        float* __restrict__ out) {
    const int tid = threadIdx.x;
    float s1 = 0.f, s2 = 0.f, sf = 0.f;
    for (int i = tid; i < BATCH * N_TOP; i += 1024) s1 += dist1[i];
    for (int i = tid; i < BATCH * M_PC; i += 1024) s2 += dist2[i];
    for (int i = tid; i < BATCH * NM_PER_B; i += 1024) {
        float d = nm[i] - fm[i];
        sf = fmaf(d, d, sf);
    }
    // pre-scale so a single reduction suffices
    float v = s1 * (1.0f / (BATCH * N_TOP))
            + s2 * (1.0f / (BATCH * M_PC))
            + sf * (1.0f / (BATCH * NM_PER_B));

    __shared__ float buf[16];
    #pragma unroll
    for (int off = 32; off >= 1; off >>= 1) v += __shfl_down(v, off, 64);
    if ((tid & 63) == 0) buf[tid >> 6] = v;
    __syncthreads();
    if (tid == 0) {
        float acc = 0.f;
        #pragma unroll
        for (int w = 0; w < 16; ++w) acc += buf[w];
        out[0] = acc;
    }
}

extern "C" void kernel_launch(void* const* d_in, const int* in_sizes, int n_in,
                              void* d_out, int out_size, void* d_ws, size_t ws_size,
                              hipStream_t stream) {
    const float* nm = (const float*)d_in[0];   // network_mesh (2,3,25,5,25)
    const float* pc = (const float*)d_in[1];   // pc (2,3,8192)
    const float* fm = (const float*)d_in[2];   // fem_mesh (2,3,25,5,25)
    float* out = (float*)d_out;

    unsigned int* dist1 = (unsigned int*)d_ws;
    unsigned int* dist2 = (unsigned int*)d_ws + DIST2_OFF;

    // init min-buffers to large positive float (0x7F7F7F7F ~ 3.39e38)
    hipMemsetAsync(d_ws, 0x7F, DIST_TOTAL_FLOATS * sizeof(float), stream);

    pair_kernel<<<848, 256, 0, stream>>>(nm, pc, dist1, dist2);
    finalize_kernel<<<1, 1024, 0, stream>>>(nm, fm, (const float*)dist1,
                                            (const float*)dist2, out);
}

// Round 2
// 92.327 us; speedup vs baseline: 1.7878x; 1.7878x over previous
//
#include <hip/hip_runtime.h>

#define BATCH 2
#define NM_PER_B 9375      // 3*25*5*25
#define C_STRIDE 3125      // 25*5*25
#define I_STRIDE 125       // 5*25
#define TOP_OFF 100        // row 4 of dim-5 axis: 4*25
#define RES 73             // (25-1)*3 + 1
#define N_TOP 5329         // 73*73
#define M_PC 8192
#define PC_PER_B 24576     // 3*8192

// Task A (dist2): 2 batches * 8 m-chunks(1024) * 32 n-segments
#define ASEG 32
#define SEG_N 167          // ceil(5329/32)
#define ABLOCKS 512
// Task B (dist1): 2 batches * 6 n-chunks(1024) * 32 m-segments
#define BSEG 32
#define SEG_M 256          // 8192/32
#define BBLOCKS 384

// ws layout (floats): dist1 [0,10658) padded to 10752; dist2 [10752,+16384)
#define DIST2_OFF 10752
#define DIST_TOTAL_FLOATS (10752 + 16384)

// Align-corners factor-3 bilinear sample of network_mesh[b,c,:,4,:] at
// refined index n = u*73 + v (axis-3 lerp first, then axis-2 — matches ref).
__device__ __forceinline__ float3 top_point(const float* __restrict__ nm, int b, int n) {
    int u = n / RES, v = n - u * RES;
    int iu = u / 3, ru = u - iu * 3;
    int iv = v / 3, rv = v - iv * 3;
    float fu = (float)ru * (1.0f / 3.0f);
    float fv = (float)rv * (1.0f / 3.0f);
    int iu2 = iu < 24 ? iu + 1 : 24;
    int iv2 = iv < 24 ? iv + 1 : 24;
    float gu = 1.0f - fu, gv = 1.0f - fv;
    const float* base = nm + b * NM_PER_B + TOP_OFF;
    float r[3];
    #pragma unroll
    for (int c = 0; c < 3; ++c) {
        const float* a = base + c * C_STRIDE;
        float a00 = a[iu * I_STRIDE + iv];
        float a01 = a[iu * I_STRIDE + iv2];
        float a10 = a[iu2 * I_STRIDE + iv];
        float a11 = a[iu2 * I_STRIDE + iv2];
        float t0 = a00 * gv + a01 * fv;
        float t1 = a10 * gv + a11 * fv;
        r[c] = t0 * gu + t1 * fu;
    }
    return make_float3(r[0], r[1], r[2]);
}

__global__ __launch_bounds__(256) void pair_kernel(const float* __restrict__ nm,
                                                   const float* __restrict__ pc,
                                                   unsigned int* __restrict__ dist1,
                                                   unsigned int* __restrict__ dist2) {
    __shared__ float4 s[SEG_M];   // (x, y, z, |q|^2); broadcast-read in inner loop
    const int blk = blockIdx.x;
    const int tid = threadIdx.x;

    if (blk < ABLOCKS) {
        // ---- task A: dist2[m] = min over one n-segment; 4 m-points/thread ----
        const int b = blk >> 8;
        const int r = blk & 255;
        const int mchunk = r >> 5;          // 0..7
        const int seg = r & 31;             // 0..31
        const int n0 = seg * SEG_N;
        const int cnt = min(SEG_N, N_TOP - n0);

        if (tid < cnt) {
            float3 p = top_point(nm, b, n0 + tid);
            s[tid] = make_float4(p.x, p.y, p.z,
                                 fmaf(p.x, p.x, fmaf(p.y, p.y, p.z * p.z)));
        }
        __syncthreads();

        const float* pcb = pc + b * PC_PER_B;
        const int m = (mchunk << 10) + tid;
        float px[4], py[4], pz[4], pn[4], mn[4];
        #pragma unroll
        for (int k = 0; k < 4; ++k) {
            int mm = m + (k << 8);
            px[k] = pcb[mm];
            py[k] = pcb[M_PC + mm];
            pz[k] = pcb[2 * M_PC + mm];
            pn[k] = fmaf(px[k], px[k], fmaf(py[k], py[k], pz[k] * pz[k]));
            mn[k] = 3.4e38f;
        }
        #pragma unroll 4
        for (int j = 0; j < cnt; ++j) {
            float4 q = s[j];
            #pragma unroll
            for (int k = 0; k < 4; ++k) {
                float t = fmaf(px[k], q.x, fmaf(py[k], q.y, pz[k] * q.z));
                mn[k] = fminf(mn[k], fmaf(-2.0f, t, q.w));
            }
        }
        #pragma unroll
        for (int k = 0; k < 4; ++k) {
            int mm = m + (k << 8);
            atomicMin(&dist2[b * M_PC + mm], __float_as_uint(mn[k] + pn[k]));
        }
    } else {
        // ---- task B: dist1[n] = min over one m-segment; 4 n-points/thread ----
        const int t = blk - ABLOCKS;
        const int b = t / 192;
        const int r = t - b * 192;
        const int nchunk = r >> 5;          // 0..5
        const int seg = r & 31;             // 0..31
        const int m0 = seg << 8;

        const float* pcb = pc + b * PC_PER_B;
        {
            int m = m0 + tid;
            float x = pcb[m], y = pcb[M_PC + m], z = pcb[2 * M_PC + m];
            s[tid] = make_float4(x, y, z, fmaf(x, x, fmaf(y, y, z * z)));
        }
        __syncthreads();

        float px[4], py[4], pz[4], pn[4], mn[4];
        int nn[4]; bool valid[4];
        #pragma unroll
        for (int k = 0; k < 4; ++k) {
            nn[k] = (nchunk << 10) + tid + (k << 8);
            valid[k] = nn[k] < N_TOP;
            float3 p = top_point(nm, b, valid[k] ? nn[k] : N_TOP - 1);
            px[k] = p.x; py[k] = p.y; pz[k] = p.z;
            pn[k] = fmaf(p.x, p.x, fmaf(p.y, p.y, p.z * p.z));
            mn[k] = 3.4e38f;
        }
        #pragma unroll 4
        for (int j = 0; j < SEG_M; ++j) {
            float4 q = s[j];
            #pragma unroll
            for (int k = 0; k < 4; ++k) {
                float t = fmaf(px[k], q.x, fmaf(py[k], q.y, pz[k] * q.z));
                mn[k] = fminf(mn[k], fmaf(-2.0f, t, q.w));
            }
        }
        #pragma unroll
        for (int k = 0; k < 4; ++k) {
            if (valid[k])
                atomicMin(&dist1[b * N_TOP + nn[k]], __float_as_uint(mn[k] + pn[k]));
        }
    }
}

__global__ __launch_bounds__(1024) void finalize_kernel(const float* __restrict__ nm,
                                                        const float* __restrict__ fm,
                                                        const float* __restrict__ dist1,
                                                        const float* __restrict__ dist2,
                                                        float* __restrict__ out) {
    const int tid = threadIdx.x;
    float s1 = 0.f, s2 = 0.f, sf = 0.f;
    for (int i = tid; i < BATCH * N_TOP; i += 1024) s1 += dist1[i];
    for (int i = tid; i < BATCH * M_PC; i += 1024) s2 += dist2[i];
    for (int i = tid; i < BATCH * NM_PER_B; i += 1024) {
        float d = nm[i] - fm[i];
        sf = fmaf(d, d, sf);
    }
    float v = s1 * (1.0f / (BATCH * N_TOP))
            + s2 * (1.0f / (BATCH * M_PC))
            + sf * (1.0f / (BATCH * NM_PER_B));

    __shared__ float buf[16];
    #pragma unroll
    for (int off = 32; off >= 1; off >>= 1) v += __shfl_down(v, off, 64);
    if ((tid & 63) == 0) buf[tid >> 6] = v;
    __syncthreads();
    if (tid == 0) {
        float acc = 0.f;
        #pragma unroll
        for (int w = 0; w < 16; ++w) acc += buf[w];
        out[0] = acc;
    }
}

extern "C" void kernel_launch(void* const* d_in, const int* in_sizes, int n_in,
                              void* d_out, int out_size, void* d_ws, size_t ws_size,
                              hipStream_t stream) {
    const float* nm = (const float*)d_in[0];   // network_mesh (2,3,25,5,25)
    const float* pc = (const float*)d_in[1];   // pc (2,3,8192)
    const float* fm = (const float*)d_in[2];   // fem_mesh (2,3,25,5,25)
    float* out = (float*)d_out;

    unsigned int* dist1 = (unsigned int*)d_ws;
    unsigned int* dist2 = (unsigned int*)d_ws + DIST2_OFF;

    hipMemsetAsync(d_ws, 0x7F, DIST_TOTAL_FLOATS * sizeof(float), stream);

    pair_kernel<<<ABLOCKS + BBLOCKS, 256, 0, stream>>>(nm, pc, dist1, dist2);
    finalize_kernel<<<1, 1024, 0, stream>>>(nm, fm, (const float*)dist1,
                                            (const float*)dist2, out);
}